// Round 9
// baseline (469.204 us; speedup 1.0000x reference)
//
#include <hip/hip_runtime.h>

#define TT 8
#define NN 50000
#define FF 128
#define HH 64
#define CC 4
#define EE 800000
#define NB2 391           // buckets of 128 nodes (ceil(50000/128))
#define CAP 2560          // padded records per (t,bucket): mean 2048, sd ~45 -> 11 sigma
#define BPT 64            // multisplit blocks per timestep

typedef unsigned short u16;
typedef unsigned int u32;
typedef __attribute__((ext_vector_type(8))) short bf16x8;
typedef __attribute__((ext_vector_type(4))) float f32x4;

static __device__ __forceinline__ float bf2f(u16 u) {
    union { unsigned int i; float f; } v; v.i = ((unsigned int)u) << 16; return v.f;
}
static __device__ __forceinline__ u16 f2bf(float f) {
    union { float f; unsigned int u; } v; v.f = f;
    unsigned int u = v.u;
    unsigned int r = u + 0x7fffu + ((u >> 16) & 1u);   // round-to-nearest-even
    return (u16)(r >> 16);
}

// ---------------- multisplit: edges -> 64B-aligned padded bucket windows ----------------
__global__ __launch_bounds__(256) void multisplit_kernel(const int* __restrict__ edges,
                                                         int* __restrict__ gcur, u32* __restrict__ binned) {
    __shared__ u32 sbuf[NB2][16];
    __shared__ int scnt[NB2];
    int bid = blockIdx.x;
    int t = bid & 7;
    int blk = bid >> 3;                       // 0..BPT-1
    const int per = (EE + BPT - 1) / BPT;     // 12500
    int e0 = blk * per;
    int e1 = e0 + per; if (e1 > EE) e1 = EE;

    for (int i = threadIdx.x; i < NB2; i += 256) scnt[i] = 0;
    __syncthreads();

    const int* es = edges + (size_t)(t * 2 + 0) * EE;
    const int* ed = edges + (size_t)(t * 2 + 1) * EE;
    int* gc = gcur + t * NB2;
    u32* bb = binned + (size_t)t * NB2 * CAP;

    for (int base = e0; base < e1; base += 256) {
        int e = base + threadIdx.x;
        u32 rec = 0; int b = -1;
        if (e < e1) {
            int src = es[e], dst = ed[e];
            b = dst >> 7;
            rec = (u32)src | ((u32)(dst & 127) << 16);
            int p = atomicAdd(&scnt[b], 1);
            if (p < 16) { sbuf[b][p] = rec; b = -1; }    // stored; else pending
        }
        __syncthreads();
        // flush any full 64B line
        for (int fb = threadIdx.x; fb < NB2; fb += 256) {
            if (scnt[fb] >= 16) {
                int g = atomicAdd(&gc[fb], 16);
                uint4* dp = (uint4*)(bb + (size_t)fb * CAP + g);
                uint4* sp = (uint4*)&sbuf[fb][0];
                dp[0] = sp[0]; dp[1] = sp[1]; dp[2] = sp[2]; dp[3] = sp[3];
                scnt[fb] = 0;                            // pendings re-append below
            }
        }
        __syncthreads();
        if (b >= 0) {                                    // pending retry (count was >16)
            int p = atomicAdd(&scnt[b], 1);
            if (p < 16) sbuf[b][p] = rec;
            else { int g = atomicAdd(&gc[b], 1); bb[(size_t)b * CAP + g] = rec; }  // ultra-rare
        }
        __syncthreads();
    }
    // residual (<16 per bucket) partial flush
    for (int fb = threadIdx.x; fb < NB2; fb += 256) {
        int c = scnt[fb];
        if (c > 0) {
            int g = atomicAdd(&gc[fb], c);
            for (int k = 0; k < c; ++k) bb[(size_t)fb * CAP + g + k] = sbuf[fb][k];
        }
    }
}

// ---------------- per-bucket: local degree hist + scan -> CSR scatter + nodeinfo + dinv ----------------
__global__ __launch_bounds__(256) void csr_scatter_kernel(const u32* __restrict__ binned, const int* __restrict__ gcur,
                                                          u16* __restrict__ srclist, u32* __restrict__ nodeinfo,
                                                          float* __restrict__ dinv) {
    __shared__ u32 recs[CAP];
    __shared__ int hist[128];
    __shared__ int cur[128];
    int b = blockIdx.x, t = blockIdx.y, tid = threadIdx.x;
    int node0 = b * 128;
    int tot = gcur[t * NB2 + b];
    const u32* win = binned + ((size_t)t * NB2 + b) * CAP;

    for (int i = tid; i < tot; i += 256) recs[i] = win[i];
    if (tid < 128) hist[tid] = 0;
    __syncthreads();
    for (int i = tid; i < tot; i += 256) atomicAdd(&hist[recs[i] >> 16], 1);
    __syncthreads();
    int h = 0;
    if (tid < 128) h = hist[tid];
    for (int off = 1; off < 128; off <<= 1) {
        int v = 0;
        if (tid < 128 && tid >= off) v = hist[tid - off];
        __syncthreads();
        if (tid < 128) hist[tid] += v;
        __syncthreads();
    }
    if (tid < 128) {
        int excl = hist[tid] - h;
        cur[tid] = excl;
        int node = node0 + tid;
        if (node < NN) {
            nodeinfo[t * NN + node] = (u32)(b * CAP + excl) | ((u32)h << 20);
            dinv[t * NN + node] = rsqrtf(1.0f + (float)h);
        }
    }
    __syncthreads();
    u16* sl = srclist + (size_t)t * NB2 * CAP;
    for (int i = tid; i < tot; i += 256) {
        u32 rec = recs[i];
        int d = rec >> 16;
        int p = atomicAdd(&cur[d], 1);
        sl[(size_t)b * CAP + p] = (u16)(rec & 0xFFFF);
    }
}

// ---------------- W transpose + bf16 convert (once per t) ----------------
__global__ __launch_bounds__(256) void wt_prep_kernel(const float* __restrict__ Wg, u16* __restrict__ wt) {
    int t = blockIdx.x;
    const float* w = Wg + t * FF * HH;
    u16* o = wt + (size_t)t * HH * FF;
    for (int i = threadIdx.x; i < FF * HH; i += 256) {
        int k = i >> 6, c = i & 63;
        o[c * FF + k] = f2bf(w[i]);
    }
}

// ---------------- y = (x @ Wg) * dinv via bf16 MFMA, stored bf16 in TWO FEATURE PLANES ----------------
// plane h (h=0: feats 0-31, h=1: feats 32-63) at y + (h*TT + t)*NN*32 -> 64B plane rows
// align exactly with cache lines (no wasted half-lines in the plane-pinned agg).
__global__ __launch_bounds__(256) void xw_kernel(const float* __restrict__ x, const u16* __restrict__ wt,
                                                 const float* __restrict__ dinv, u16* __restrict__ y) {
    int t = blockIdx.y;
    int row0 = blockIdx.x * 64;
    int tid = threadIdx.x;
    __shared__ __align__(16) u16 xlds[64 * 128];
    __shared__ __align__(16) u16 wlds[64 * 128];

    // stage Wt (16KB bf16, L2-resident)
    const uint4* wsrc = reinterpret_cast<const uint4*>(wt + (size_t)t * HH * FF);
    #pragma unroll
    for (int it = 0; it < 4; ++it) {
        int idx = it * 256 + tid;            // uint4 index (1024 total)
        int c = idx >> 4;
        int k = (idx & 15) * 8;
        *reinterpret_cast<uint4*>(&wlds[c * FF + (k ^ ((c & 7) << 3))]) = wsrc[idx];
    }
    // stage x tile, fp32 -> bf16
    const float* xt = x + (size_t)t * NN * FF;
    #pragma unroll
    for (int it = 0; it < 8; ++it) {
        int idx = it * 256 + tid;            // float4 index (2048 total)
        int r = idx >> 5, k4 = (idx & 31) * 4;
        int row = row0 + r;
        float4 v = make_float4(0.f, 0.f, 0.f, 0.f);
        if (row < NN) v = *reinterpret_cast<const float4*>(&xt[(size_t)row * FF + k4]);
        uint2 p;
        p.x = (u32)f2bf(v.x) | ((u32)f2bf(v.y) << 16);
        p.y = (u32)f2bf(v.z) | ((u32)f2bf(v.w) << 16);
        *reinterpret_cast<uint2*>(&xlds[r * FF + (k4 ^ ((r & 7) << 3))]) = p;
    }
    __syncthreads();

    int w = tid >> 6, lane = tid & 63;
    int wr = w * 16;
    int l15 = lane & 15, lg = lane >> 4;
    int sw = (l15 & 7) << 3;
    f32x4 d[4] = {{0,0,0,0},{0,0,0,0},{0,0,0,0},{0,0,0,0}};
    #pragma unroll
    for (int k0 = 0; k0 < 128; k0 += 32) {
        int kbs = (k0 + lg * 8) ^ sw;
        bf16x8 af = *reinterpret_cast<const bf16x8*>(&xlds[(wr + l15) * FF + kbs]);
        #pragma unroll
        for (int n = 0; n < 4; ++n) {
            bf16x8 bf = *reinterpret_cast<const bf16x8*>(&wlds[(n * 16 + l15) * FF + kbs]);
            d[n] = __builtin_amdgcn_mfma_f32_16x16x32_bf16(af, bf, d[n], 0, 0, 0);
        }
    }
    // epilogue: * dinv, -> bf16 planes
    int rbase = row0 + wr + lg * 4;
    float dv[4];
    #pragma unroll
    for (int i = 0; i < 4; ++i) {
        int grow = rbase + i;
        dv[i] = (grow < NN) ? dinv[t * NN + grow] : 0.f;
    }
    #pragma unroll
    for (int n = 0; n < 4; ++n) {
        int col = n * 16 + l15;
        int hpl = col >> 5, cp = col & 31;
        u16* ypl = y + ((size_t)(hpl * TT + t) * NN) * 32;
        #pragma unroll
        for (int i = 0; i < 4; ++i) {
            int grow = rbase + i;
            if (grow < NN) ypl[(size_t)grow * 32 + cp] = f2bf(d[n][i] * dv[i]);
        }
    }
}

// ---------------- gather-aggregate, plane pinned to XCD group (single dispatch) ----------------
// blocks dispatch round-robin over XCDs (bid&7 = XCD): plane = (bid>>2)&1 puts feats 0-31
// on XCDs 0-3 and feats 32-63 on XCDs 4-7. Per-XCD footprint = 8 x 3.2MB plane slices; the
// active t-slice fits the 4MB XCD L2 -> capacity misses vanish (fetch floor ~205MB vs 401).
// wave = 1 node; lane = (slot=lane>>3, quad=lane&7): one uint2 (8B) x 8 lanes = full 64B
// plane row; 8 rows per instruction; shfl_xor(8,16,32) folds slots.
__global__ __launch_bounds__(256) void agg_kernel(const u16* __restrict__ y, const float* __restrict__ dinv,
                                                  const u32* __restrict__ nodeinfo, const u16* __restrict__ srclist,
                                                  const float* __restrict__ bg, float* __restrict__ acc) {
    int bid = blockIdx.x;
    int h = (bid >> 2) & 1;                                   // plane <- XCD group
    int node = ((bid >> 3) * 4 + (bid & 3)) * 4 + (threadIdx.x >> 6);
    int lane = threadIdx.x & 63;
    int sub = lane >> 3;            // edge slot 0..7
    int fo = lane & 7;              // feature quad within plane: feats fo*4 .. fo*4+3
    float a0 = 0.f, a1 = 0.f, a2 = 0.f, a3 = 0.f;
    for (int t = 0; t < TT; ++t) {
        const u16* yp = y + ((size_t)(h * TT + t) * NN) * 32;
        u32 info = nodeinfo[t * NN + node];
        int cnt = info >> 20;
        const u16* sl = srclist + (size_t)t * NB2 * CAP + (info & 0xFFFFF);
        float s0 = 0.f, s1 = 0.f, s2 = 0.f, s3 = 0.f;
        int j = 0;
        for (; j + 16 <= cnt; j += 16) {
            int e0 = sl[j + sub], e1 = sl[j + 8 + sub];
            uint2 v0 = *reinterpret_cast<const uint2*>(&yp[(size_t)e0 * 32 + fo * 4]);
            uint2 v1 = *reinterpret_cast<const uint2*>(&yp[(size_t)e1 * 32 + fo * 4]);
            s0 += bf2f((u16)(v0.x & 0xFFFF)) + bf2f((u16)(v1.x & 0xFFFF));
            s1 += bf2f((u16)(v0.x >> 16))    + bf2f((u16)(v1.x >> 16));
            s2 += bf2f((u16)(v0.y & 0xFFFF)) + bf2f((u16)(v1.y & 0xFFFF));
            s3 += bf2f((u16)(v0.y >> 16))    + bf2f((u16)(v1.y >> 16));
        }
        for (; j < cnt; j += 8) {
            int e = j + sub;
            uint2 v = make_uint2(0u, 0u);
            if (e < cnt) {
                int srcid = sl[e];
                v = *reinterpret_cast<const uint2*>(&yp[(size_t)srcid * 32 + fo * 4]);
            }
            s0 += bf2f((u16)(v.x & 0xFFFF));
            s1 += bf2f((u16)(v.x >> 16));
            s2 += bf2f((u16)(v.y & 0xFFFF));
            s3 += bf2f((u16)(v.y >> 16));
        }
        s0 += __shfl_xor(s0, 8, 64); s0 += __shfl_xor(s0, 16, 64); s0 += __shfl_xor(s0, 32, 64);
        s1 += __shfl_xor(s1, 8, 64); s1 += __shfl_xor(s1, 16, 64); s1 += __shfl_xor(s1, 32, 64);
        s2 += __shfl_xor(s2, 8, 64); s2 += __shfl_xor(s2, 16, 64); s2 += __shfl_xor(s2, 32, 64);
        s3 += __shfl_xor(s3, 8, 64); s3 += __shfl_xor(s3, 16, 64); s3 += __shfl_xor(s3, 32, 64);
        // self loop (y already scaled by src dinv)
        uint2 sv = *reinterpret_cast<const uint2*>(&yp[(size_t)node * 32 + fo * 4]);
        s0 += bf2f((u16)(sv.x & 0xFFFF));
        s1 += bf2f((u16)(sv.x >> 16));
        s2 += bf2f((u16)(sv.y & 0xFFFF));
        s3 += bf2f((u16)(sv.y >> 16));
        float dvv = dinv[t * NN + node];
        float4 bgv = *reinterpret_cast<const float4*>(&bg[t * HH + h * 32 + fo * 4]);
        a0 += fmaxf(dvv * s0 + bgv.x, 0.f);
        a1 += fmaxf(dvv * s1 + bgv.y, 0.f);
        a2 += fmaxf(dvv * s2 + bgv.z, 0.f);
        a3 += fmaxf(dvv * s3 + bgv.w, 0.f);
    }
    if (sub == 0) {
        float4 o = make_float4(a0, a1, a2, a3);
        *reinterpret_cast<float4*>(&acc[(size_t)node * HH + h * 32 + fo * 4]) = o;
    }
}

// ---------------- per-node MLP head + log_softmax ----------------
__global__ __launch_bounds__(256) void head_kernel(const float* __restrict__ acc,
                                                   const float* __restrict__ W1, const float* __restrict__ b1,
                                                   const float* __restrict__ W2, const float* __restrict__ b2,
                                                   const float* __restrict__ W3, const float* __restrict__ b3,
                                                   float* __restrict__ out) {
    __shared__ float w1[64 * 32], w2[32 * 16], w3[16 * 4], bb1[32], bb2[16], bb3[4];
    int tid = threadIdx.x;
    for (int i = tid; i < 2048; i += 256) w1[i] = W1[i];
    for (int i = tid; i < 512; i += 256) w2[i] = W2[i];
    if (tid < 64) w3[tid] = W3[tid];
    if (tid < 32) bb1[tid] = b1[tid];
    if (tid < 16) bb2[tid] = b2[tid];
    if (tid < 4) bb3[tid] = b3[tid];
    __syncthreads();
    int node = blockIdx.x * 256 + tid;
    if (node >= NN) return;

    float a[64];
    #pragma unroll
    for (int k = 0; k < 64; ++k) a[k] = acc[(size_t)node * HH + k];

    float h1[32];
    for (int j = 0; j < 32; ++j) {
        float s = bb1[j];
        #pragma unroll
        for (int k = 0; k < 64; ++k) s += a[k] * w1[k * 32 + j];
        h1[j] = fmaxf(s, 0.f);
    }
    float h2[16];
    for (int j = 0; j < 16; ++j) {
        float s = bb2[j];
        #pragma unroll
        for (int k = 0; k < 32; ++k) s += h1[k] * w2[k * 16 + j];
        h2[j] = fmaxf(s, 0.f);
    }
    float l[4];
    for (int c = 0; c < 4; ++c) {
        float s = bb3[c];
        #pragma unroll
        for (int k = 0; k < 16; ++k) s += h2[k] * w3[k * 4 + c];
        l[c] = s;
    }
    float m = fmaxf(fmaxf(l[0], l[1]), fmaxf(l[2], l[3]));
    float sum = 0.f;
    #pragma unroll
    for (int c = 0; c < 4; ++c) sum += expf(l[c] - m);
    float lse = logf(sum);
    float4 o;
    o.x = l[0] - m - lse; o.y = l[1] - m - lse; o.z = l[2] - m - lse; o.w = l[3] - m - lse;
    *reinterpret_cast<float4*>(&out[(size_t)node * CC]) = o;
}

extern "C" void kernel_launch(void* const* d_in, const int* in_sizes, int n_in,
                              void* d_out, int out_size, void* d_ws, size_t ws_size,
                              hipStream_t stream) {
    const float* x    = (const float*)d_in[0];
    const int*  edges = (const int*)d_in[1];
    const float* Wg   = (const float*)d_in[2];
    const float* bg   = (const float*)d_in[3];
    const float* W1   = (const float*)d_in[4];
    const float* b1   = (const float*)d_in[5];
    const float* W2   = (const float*)d_in[6];
    const float* b2   = (const float*)d_in[7];
    const float* W3   = (const float*)d_in[8];
    const float* b3   = (const float*)d_in[9];
    float* out = (float*)d_out;

    char* ws = (char*)d_ws;
    size_t o = 0;
    int* gcur      = (int*)(ws + o); o += (size_t)TT * NB2 * 4;            // 12.5 KB
    o = (o + 255) & ~(size_t)255;
    float* dinv    = (float*)(ws + o); o += (size_t)TT * NN * 4;           // 1.6 MB
    u32* nodeinfo  = (u32*)(ws + o); o += (size_t)TT * NN * 4;             // 1.6 MB
    o = (o + 255) & ~(size_t)255;
    u16* wt        = (u16*)(ws + o); o += (size_t)TT * HH * FF * 2;        // 128 KB
    o = (o + 255) & ~(size_t)255;
    u32* binned    = (u32*)(ws + o); o += (size_t)TT * NB2 * CAP * 4;      // 32.0 MB
    u16* srclist   = (u16*)(ws + o); o += (size_t)TT * NB2 * CAP * 2;      // 16.0 MB
    u16* y         = (u16*)(ws + o); o += (size_t)2 * TT * NN * 32 * 2;    // 51.2 MB (2 planes)
    float* acc     = (float*)(ws + o); o += (size_t)NN * HH * 4;           // 12.8 MB
    // total ~115 MB

    hipMemsetAsync(gcur, 0, (size_t)TT * NB2 * 4, stream);

    multisplit_kernel<<<BPT * TT, 256, 0, stream>>>(edges, gcur, binned);

    dim3 gsc(NB2, TT);
    csr_scatter_kernel<<<gsc, 256, 0, stream>>>(binned, gcur, srclist, nodeinfo, dinv);

    wt_prep_kernel<<<TT, 256, 0, stream>>>(Wg, wt);

    dim3 gx(782, TT);
    xw_kernel<<<gx, 256, 0, stream>>>(x, wt, dinv, y);

    // single dispatch, plane pinned to XCD group via bid&7 round-robin
    agg_kernel<<<25000, 256, 0, stream>>>(y, dinv, nodeinfo, srclist, bg, acc);

    head_kernel<<<196, 256, 0, stream>>>(acc, W1, b1, W2, b2, W3, b3, out);
}

// Round 10
// 428.752 us; speedup vs baseline: 1.0943x; 1.0943x over previous
//
#include <hip/hip_runtime.h>

#define TT 8
#define NN 50000
#define FF 128
#define HH 64
#define CC 4
#define EE 800000
#define NB2 391           // buckets of 128 nodes (ceil(50000/128))
#define CAP 2560          // padded records per (t,bucket): mean 2048, sd ~45 -> 11 sigma
#define BPT 64            // multisplit blocks per timestep

typedef unsigned short u16;
typedef unsigned int u32;
typedef __attribute__((ext_vector_type(8))) short bf16x8;
typedef __attribute__((ext_vector_type(4))) float f32x4;

static __device__ __forceinline__ float bf2f(u16 u) {
    union { unsigned int i; float f; } v; v.i = ((unsigned int)u) << 16; return v.f;
}
static __device__ __forceinline__ float bflo(u32 w) {
    union { unsigned int i; float f; } v; v.i = w << 16; return v.f;
}
static __device__ __forceinline__ float bfhi(u32 w) {
    union { unsigned int i; float f; } v; v.i = w & 0xFFFF0000u; return v.f;
}
static __device__ __forceinline__ u16 f2bf(float f) {
    union { float f; unsigned int u; } v; v.f = f;
    unsigned int u = v.u;
    unsigned int r = u + 0x7fffu + ((u >> 16) & 1u);   // round-to-nearest-even
    return (u16)(r >> 16);
}

// ---------------- multisplit: edges -> 64B-aligned padded bucket windows ----------------
// LDS line buffers; only full aligned 64B lines flushed. 512 edges staged per flush
// round (2/thread) -> half the barriers/sweeps of the 256-edge version.
__global__ __launch_bounds__(256) void multisplit_kernel(const int* __restrict__ edges,
                                                         int* __restrict__ gcur, u32* __restrict__ binned) {
    __shared__ u32 sbuf[NB2][16];
    __shared__ int scnt[NB2];
    int bid = blockIdx.x;
    int t = bid & 7;
    int blk = bid >> 3;                       // 0..BPT-1
    const int per = (EE + BPT - 1) / BPT;     // 12500
    int e0 = blk * per;
    int e1 = e0 + per; if (e1 > EE) e1 = EE;

    for (int i = threadIdx.x; i < NB2; i += 256) scnt[i] = 0;
    __syncthreads();

    const int* es = edges + (size_t)(t * 2 + 0) * EE;
    const int* ed = edges + (size_t)(t * 2 + 1) * EE;
    int* gc = gcur + t * NB2;
    u32* bb = binned + (size_t)t * NB2 * CAP;

    for (int base = e0; base < e1; base += 512) {
        u32 recA = 0, recB = 0; int bA = -1, bB = -1;
        int eA = base + threadIdx.x;
        int eB = base + 256 + threadIdx.x;
        if (eA < e1) {
            int src = es[eA], dst = ed[eA];
            bA = dst >> 7;
            recA = (u32)src | ((u32)(dst & 127) << 16);
            int p = atomicAdd(&scnt[bA], 1);
            if (p < 16) { sbuf[bA][p] = recA; bA = -1; }
        }
        if (eB < e1) {
            int src = es[eB], dst = ed[eB];
            bB = dst >> 7;
            recB = (u32)src | ((u32)(dst & 127) << 16);
            int p = atomicAdd(&scnt[bB], 1);
            if (p < 16) { sbuf[bB][p] = recB; bB = -1; }
        }
        __syncthreads();
        // flush any full 64B line
        for (int fb = threadIdx.x; fb < NB2; fb += 256) {
            if (scnt[fb] >= 16) {
                int g = atomicAdd(&gc[fb], 16);
                uint4* dp = (uint4*)(bb + (size_t)fb * CAP + g);
                uint4* sp = (uint4*)&sbuf[fb][0];
                dp[0] = sp[0]; dp[1] = sp[1]; dp[2] = sp[2]; dp[3] = sp[3];
                scnt[fb] = 0;                            // pendings re-append below
            }
        }
        __syncthreads();
        if (bA >= 0) {                                   // pending retry (count was >16)
            int p = atomicAdd(&scnt[bA], 1);
            if (p < 16) sbuf[bA][p] = recA;
            else { int g = atomicAdd(&gc[bA], 1); bb[(size_t)bA * CAP + g] = recA; }  // ultra-rare
        }
        if (bB >= 0) {
            int p = atomicAdd(&scnt[bB], 1);
            if (p < 16) sbuf[bB][p] = recB;
            else { int g = atomicAdd(&gc[bB], 1); bb[(size_t)bB * CAP + g] = recB; }
        }
        __syncthreads();
    }
    // residual (<16 per bucket) partial flush
    for (int fb = threadIdx.x; fb < NB2; fb += 256) {
        int c = scnt[fb];
        if (c > 0) {
            int g = atomicAdd(&gc[fb], c);
            for (int k = 0; k < c; ++k) bb[(size_t)fb * CAP + g + k] = sbuf[fb][k];
        }
    }
}

// ---------------- per-bucket: local degree hist + scan -> CSR scatter + nodeinfo + dinv ----------------
__global__ __launch_bounds__(256) void csr_scatter_kernel(const u32* __restrict__ binned, const int* __restrict__ gcur,
                                                          u16* __restrict__ srclist, u32* __restrict__ nodeinfo,
                                                          float* __restrict__ dinv) {
    __shared__ u32 recs[CAP];
    __shared__ int hist[128];
    __shared__ int cur[128];
    int b = blockIdx.x, t = blockIdx.y, tid = threadIdx.x;
    int node0 = b * 128;
    int tot = gcur[t * NB2 + b];
    const u32* win = binned + ((size_t)t * NB2 + b) * CAP;

    for (int i = tid; i < tot; i += 256) recs[i] = win[i];
    if (tid < 128) hist[tid] = 0;
    __syncthreads();
    for (int i = tid; i < tot; i += 256) atomicAdd(&hist[recs[i] >> 16], 1);
    __syncthreads();
    int h = 0;
    if (tid < 128) h = hist[tid];
    for (int off = 1; off < 128; off <<= 1) {
        int v = 0;
        if (tid < 128 && tid >= off) v = hist[tid - off];
        __syncthreads();
        if (tid < 128) hist[tid] += v;
        __syncthreads();
    }
    if (tid < 128) {
        int excl = hist[tid] - h;
        cur[tid] = excl;
        int node = node0 + tid;
        if (node < NN) {
            nodeinfo[t * NN + node] = (u32)(b * CAP + excl) | ((u32)h << 20);
            dinv[t * NN + node] = rsqrtf(1.0f + (float)h);
        }
    }
    __syncthreads();
    u16* sl = srclist + (size_t)t * NB2 * CAP;
    for (int i = tid; i < tot; i += 256) {
        u32 rec = recs[i];
        int d = rec >> 16;
        int p = atomicAdd(&cur[d], 1);
        sl[(size_t)b * CAP + p] = (u16)(rec & 0xFFFF);
    }
}

// ---------------- W transpose + bf16 convert (once per t) ----------------
__global__ __launch_bounds__(256) void wt_prep_kernel(const float* __restrict__ Wg, u16* __restrict__ wt) {
    int t = blockIdx.x;
    const float* w = Wg + t * FF * HH;
    u16* o = wt + (size_t)t * HH * FF;
    for (int i = threadIdx.x; i < FF * HH; i += 256) {
        int k = i >> 6, c = i & 63;
        o[c * FF + k] = f2bf(w[i]);
    }
}

// ---------------- y = (x @ Wg) * dinv via bf16 MFMA, stored bf16 [T][N][64] ----------------
__global__ __launch_bounds__(256) void xw_kernel(const float* __restrict__ x, const u16* __restrict__ wt,
                                                 const float* __restrict__ dinv, u16* __restrict__ y) {
    int t = blockIdx.y;
    int row0 = blockIdx.x * 64;
    int tid = threadIdx.x;
    __shared__ __align__(16) u16 xlds[64 * 128];
    __shared__ __align__(16) u16 wlds[64 * 128];

    // stage Wt (16KB bf16, L2-resident)
    const uint4* wsrc = reinterpret_cast<const uint4*>(wt + (size_t)t * HH * FF);
    #pragma unroll
    for (int it = 0; it < 4; ++it) {
        int idx = it * 256 + tid;            // uint4 index (1024 total)
        int c = idx >> 4;
        int k = (idx & 15) * 8;
        *reinterpret_cast<uint4*>(&wlds[c * FF + (k ^ ((c & 7) << 3))]) = wsrc[idx];
    }
    // stage x tile, fp32 -> bf16
    const float* xt = x + (size_t)t * NN * FF;
    #pragma unroll
    for (int it = 0; it < 8; ++it) {
        int idx = it * 256 + tid;            // float4 index (2048 total)
        int r = idx >> 5, k4 = (idx & 31) * 4;
        int row = row0 + r;
        float4 v = make_float4(0.f, 0.f, 0.f, 0.f);
        if (row < NN) v = *reinterpret_cast<const float4*>(&xt[(size_t)row * FF + k4]);
        uint2 p;
        p.x = (u32)f2bf(v.x) | ((u32)f2bf(v.y) << 16);
        p.y = (u32)f2bf(v.z) | ((u32)f2bf(v.w) << 16);
        *reinterpret_cast<uint2*>(&xlds[r * FF + (k4 ^ ((r & 7) << 3))]) = p;
    }
    __syncthreads();

    int w = tid >> 6, lane = tid & 63;
    int wr = w * 16;
    int l15 = lane & 15, lg = lane >> 4;
    int sw = (l15 & 7) << 3;
    f32x4 d[4] = {{0,0,0,0},{0,0,0,0},{0,0,0,0},{0,0,0,0}};
    #pragma unroll
    for (int k0 = 0; k0 < 128; k0 += 32) {
        int kbs = (k0 + lg * 8) ^ sw;
        bf16x8 af = *reinterpret_cast<const bf16x8*>(&xlds[(wr + l15) * FF + kbs]);
        #pragma unroll
        for (int n = 0; n < 4; ++n) {
            bf16x8 bf = *reinterpret_cast<const bf16x8*>(&wlds[(n * 16 + l15) * FF + kbs]);
            d[n] = __builtin_amdgcn_mfma_f32_16x16x32_bf16(af, bf, d[n], 0, 0, 0);
        }
    }
    // epilogue: * dinv -> bf16 row-major [N][64]
    int rbase = row0 + wr + lg * 4;
    float dv[4];
    #pragma unroll
    for (int i = 0; i < 4; ++i) {
        int grow = rbase + i;
        dv[i] = (grow < NN) ? dinv[t * NN + grow] : 0.f;
    }
    u16* yt = y + (size_t)t * NN * HH;
    #pragma unroll
    for (int n = 0; n < 4; ++n) {
        int col = n * 16 + l15;
        #pragma unroll
        for (int i = 0; i < 4; ++i) {
            int grow = rbase + i;
            if (grow < NN) yt[(size_t)grow * HH + col] = f2bf(d[n][i] * dv[i]);
        }
    }
}

// ---------------- gather-aggregate over all T (single pass, full 128B rows) ----------------
// wave = 1 node; lane = (slot=lane>>4, quad=lane&15). Main loop: 32 edges/iter, each slot
// reads 8 CONSECUTIVE srclist indices (coalesced) and keeps 8 independent row-gathers in
// flight (r8 had 4; r9 showed the random path sustains 2.78TB/s with more MLP).
__global__ __launch_bounds__(256) void agg_kernel(const u16* __restrict__ y, const float* __restrict__ dinv,
                                                  const u32* __restrict__ nodeinfo, const u16* __restrict__ srclist,
                                                  const float* __restrict__ bg, float* __restrict__ acc) {
    int node = blockIdx.x * 4 + (threadIdx.x >> 6);
    int lane = threadIdx.x & 63;
    int sub = lane >> 4;            // slot 0..3
    int fo = lane & 15;             // feature quad: feats fo*4 .. fo*4+3
    float a0 = 0.f, a1 = 0.f, a2 = 0.f, a3 = 0.f;
    for (int t = 0; t < TT; ++t) {
        const u16* yt = y + (size_t)t * NN * HH;
        u32 info = nodeinfo[t * NN + node];
        int cnt = info >> 20;
        const u16* sl = srclist + (size_t)t * NB2 * CAP + (info & 0xFFFFF);
        float s0 = 0.f, s1 = 0.f, s2 = 0.f, s3 = 0.f;
        int j = 0;
        for (; j + 32 <= cnt; j += 32) {
            const u16* sb = sl + j + sub * 8;
            int e0 = sb[0], e1 = sb[1], e2 = sb[2], e3 = sb[3];
            int e4 = sb[4], e5 = sb[5], e6 = sb[6], e7 = sb[7];
            uint2 v0 = *reinterpret_cast<const uint2*>(&yt[(size_t)e0 * HH + fo * 4]);
            uint2 v1 = *reinterpret_cast<const uint2*>(&yt[(size_t)e1 * HH + fo * 4]);
            uint2 v2 = *reinterpret_cast<const uint2*>(&yt[(size_t)e2 * HH + fo * 4]);
            uint2 v3 = *reinterpret_cast<const uint2*>(&yt[(size_t)e3 * HH + fo * 4]);
            uint2 v4 = *reinterpret_cast<const uint2*>(&yt[(size_t)e4 * HH + fo * 4]);
            uint2 v5 = *reinterpret_cast<const uint2*>(&yt[(size_t)e5 * HH + fo * 4]);
            uint2 v6 = *reinterpret_cast<const uint2*>(&yt[(size_t)e6 * HH + fo * 4]);
            uint2 v7 = *reinterpret_cast<const uint2*>(&yt[(size_t)e7 * HH + fo * 4]);
            s0 += (bflo(v0.x) + bflo(v1.x)) + (bflo(v2.x) + bflo(v3.x))
                + (bflo(v4.x) + bflo(v5.x)) + (bflo(v6.x) + bflo(v7.x));
            s1 += (bfhi(v0.x) + bfhi(v1.x)) + (bfhi(v2.x) + bfhi(v3.x))
                + (bfhi(v4.x) + bfhi(v5.x)) + (bfhi(v6.x) + bfhi(v7.x));
            s2 += (bflo(v0.y) + bflo(v1.y)) + (bflo(v2.y) + bflo(v3.y))
                + (bflo(v4.y) + bflo(v5.y)) + (bflo(v6.y) + bflo(v7.y));
            s3 += (bfhi(v0.y) + bfhi(v1.y)) + (bfhi(v2.y) + bfhi(v3.y))
                + (bfhi(v4.y) + bfhi(v5.y)) + (bfhi(v6.y) + bfhi(v7.y));
        }
        for (; j < cnt; j += 4) {
            int e = j + sub;
            uint2 v = make_uint2(0u, 0u);
            if (e < cnt) {
                int srcid = sl[e];
                v = *reinterpret_cast<const uint2*>(&yt[(size_t)srcid * HH + fo * 4]);
            }
            s0 += bflo(v.x);
            s1 += bfhi(v.x);
            s2 += bflo(v.y);
            s3 += bfhi(v.y);
        }
        s0 += __shfl_xor(s0, 16, 64); s0 += __shfl_xor(s0, 32, 64);
        s1 += __shfl_xor(s1, 16, 64); s1 += __shfl_xor(s1, 32, 64);
        s2 += __shfl_xor(s2, 16, 64); s2 += __shfl_xor(s2, 32, 64);
        s3 += __shfl_xor(s3, 16, 64); s3 += __shfl_xor(s3, 32, 64);
        // self loop (y already scaled by src dinv)
        uint2 sv = *reinterpret_cast<const uint2*>(&yt[(size_t)node * HH + fo * 4]);
        s0 += bflo(sv.x);
        s1 += bfhi(sv.x);
        s2 += bflo(sv.y);
        s3 += bfhi(sv.y);
        float dvv = dinv[t * NN + node];
        float4 bgv = *reinterpret_cast<const float4*>(&bg[t * HH + fo * 4]);
        a0 += fmaxf(dvv * s0 + bgv.x, 0.f);
        a1 += fmaxf(dvv * s1 + bgv.y, 0.f);
        a2 += fmaxf(dvv * s2 + bgv.z, 0.f);
        a3 += fmaxf(dvv * s3 + bgv.w, 0.f);
    }
    if (sub == 0) {
        float4 o = make_float4(a0, a1, a2, a3);
        *reinterpret_cast<float4*>(&acc[(size_t)node * HH + fo * 4]) = o;
    }
}

// ---------------- per-node MLP head + log_softmax ----------------
__global__ __launch_bounds__(256) void head_kernel(const float* __restrict__ acc,
                                                   const float* __restrict__ W1, const float* __restrict__ b1,
                                                   const float* __restrict__ W2, const float* __restrict__ b2,
                                                   const float* __restrict__ W3, const float* __restrict__ b3,
                                                   float* __restrict__ out) {
    __shared__ float w1[64 * 32], w2[32 * 16], w3[16 * 4], bb1[32], bb2[16], bb3[4];
    int tid = threadIdx.x;
    for (int i = tid; i < 2048; i += 256) w1[i] = W1[i];
    for (int i = tid; i < 512; i += 256) w2[i] = W2[i];
    if (tid < 64) w3[tid] = W3[tid];
    if (tid < 32) bb1[tid] = b1[tid];
    if (tid < 16) bb2[tid] = b2[tid];
    if (tid < 4) bb3[tid] = b3[tid];
    __syncthreads();
    int node = blockIdx.x * 256 + tid;
    if (node >= NN) return;

    float a[64];
    #pragma unroll
    for (int k = 0; k < 64; ++k) a[k] = acc[(size_t)node * HH + k];

    float h1[32];
    for (int j = 0; j < 32; ++j) {
        float s = bb1[j];
        #pragma unroll
        for (int k = 0; k < 64; ++k) s += a[k] * w1[k * 32 + j];
        h1[j] = fmaxf(s, 0.f);
    }
    float h2[16];
    for (int j = 0; j < 16; ++j) {
        float s = bb2[j];
        #pragma unroll
        for (int k = 0; k < 32; ++k) s += h1[k] * w2[k * 16 + j];
        h2[j] = fmaxf(s, 0.f);
    }
    float l[4];
    for (int c = 0; c < 4; ++c) {
        float s = bb3[c];
        #pragma unroll
        for (int k = 0; k < 16; ++k) s += h2[k] * w3[k * 4 + c];
        l[c] = s;
    }
    float m = fmaxf(fmaxf(l[0], l[1]), fmaxf(l[2], l[3]));
    float sum = 0.f;
    #pragma unroll
    for (int c = 0; c < 4; ++c) sum += expf(l[c] - m);
    float lse = logf(sum);
    float4 o;
    o.x = l[0] - m - lse; o.y = l[1] - m - lse; o.z = l[2] - m - lse; o.w = l[3] - m - lse;
    *reinterpret_cast<float4*>(&out[(size_t)node * CC]) = o;
}

extern "C" void kernel_launch(void* const* d_in, const int* in_sizes, int n_in,
                              void* d_out, int out_size, void* d_ws, size_t ws_size,
                              hipStream_t stream) {
    const float* x    = (const float*)d_in[0];
    const int*  edges = (const int*)d_in[1];
    const float* Wg   = (const float*)d_in[2];
    const float* bg   = (const float*)d_in[3];
    const float* W1   = (const float*)d_in[4];
    const float* b1   = (const float*)d_in[5];
    const float* W2   = (const float*)d_in[6];
    const float* b2   = (const float*)d_in[7];
    const float* W3   = (const float*)d_in[8];
    const float* b3   = (const float*)d_in[9];
    float* out = (float*)d_out;

    char* ws = (char*)d_ws;
    size_t o = 0;
    int* gcur      = (int*)(ws + o); o += (size_t)TT * NB2 * 4;            // 12.5 KB
    o = (o + 255) & ~(size_t)255;
    float* dinv    = (float*)(ws + o); o += (size_t)TT * NN * 4;           // 1.6 MB
    u32* nodeinfo  = (u32*)(ws + o); o += (size_t)TT * NN * 4;             // 1.6 MB
    o = (o + 255) & ~(size_t)255;
    u16* wt        = (u16*)(ws + o); o += (size_t)TT * HH * FF * 2;        // 128 KB
    o = (o + 255) & ~(size_t)255;
    u32* binned    = (u32*)(ws + o); o += (size_t)TT * NB2 * CAP * 4;      // 32.0 MB
    u16* srclist   = (u16*)(ws + o); o += (size_t)TT * NB2 * CAP * 2;      // 16.0 MB
    u16* y         = (u16*)(ws + o); o += (size_t)TT * NN * HH * 2;        // 51.2 MB
    float* acc     = (float*)(ws + o); o += (size_t)NN * HH * 4;           // 12.8 MB
    // total ~115 MB

    hipMemsetAsync(gcur, 0, (size_t)TT * NB2 * 4, stream);

    multisplit_kernel<<<BPT * TT, 256, 0, stream>>>(edges, gcur, binned);

    dim3 gsc(NB2, TT);
    csr_scatter_kernel<<<gsc, 256, 0, stream>>>(binned, gcur, srclist, nodeinfo, dinv);

    wt_prep_kernel<<<TT, 256, 0, stream>>>(Wg, wt);

    dim3 gx(782, TT);
    xw_kernel<<<gx, 256, 0, stream>>>(x, wt, dinv, y);

    agg_kernel<<<12500, 256, 0, stream>>>(y, dinv, nodeinfo, srclist, bg, acc);

    head_kernel<<<196, 256, 0, stream>>>(acc, W1, b1, W2, b2, W3, b3, out);
}

// Round 11
// 390.779 us; speedup vs baseline: 1.2007x; 1.0972x over previous
//
#include <hip/hip_runtime.h>

#define TT 8
#define NN 50000
#define FF 128
#define HH 64
#define CC 4
#define EE 800000
#define NB2 391           // buckets of 128 nodes (ceil(50000/128))
#define CAP 2560          // padded records per (t,bucket): mean 2048, sd ~45 -> 11 sigma
#define BPT 64            // multisplit blocks per timestep

typedef unsigned short u16;
typedef unsigned int u32;
typedef __attribute__((ext_vector_type(8))) short bf16x8;
typedef __attribute__((ext_vector_type(4))) float f32x4;

static __device__ __forceinline__ float bf2f(u16 u) {
    union { unsigned int i; float f; } v; v.i = ((unsigned int)u) << 16; return v.f;
}
static __device__ __forceinline__ float bflo(u32 w) {
    union { unsigned int i; float f; } v; v.i = w << 16; return v.f;
}
static __device__ __forceinline__ float bfhi(u32 w) {
    union { unsigned int i; float f; } v; v.i = w & 0xFFFF0000u; return v.f;
}
static __device__ __forceinline__ u16 f2bf(float f) {
    union { float f; unsigned int u; } v; v.f = f;
    unsigned int u = v.u;
    unsigned int r = u + 0x7fffu + ((u >> 16) & 1u);   // round-to-nearest-even
    return (u16)(r >> 16);
}

// ---------------- multisplit: edges -> 64B-aligned padded bucket windows ----------------
// LDS line buffers; only full aligned 64B lines flushed. 512 edges staged per flush round.
__global__ __launch_bounds__(256) void multisplit_kernel(const int* __restrict__ edges,
                                                         int* __restrict__ gcur, u32* __restrict__ binned) {
    __shared__ u32 sbuf[NB2][16];
    __shared__ int scnt[NB2];
    int bid = blockIdx.x;
    int t = bid & 7;
    int blk = bid >> 3;                       // 0..BPT-1
    const int per = (EE + BPT - 1) / BPT;     // 12500
    int e0 = blk * per;
    int e1 = e0 + per; if (e1 > EE) e1 = EE;

    for (int i = threadIdx.x; i < NB2; i += 256) scnt[i] = 0;
    __syncthreads();

    const int* es = edges + (size_t)(t * 2 + 0) * EE;
    const int* ed = edges + (size_t)(t * 2 + 1) * EE;
    int* gc = gcur + t * NB2;
    u32* bb = binned + (size_t)t * NB2 * CAP;

    for (int base = e0; base < e1; base += 512) {
        u32 recA = 0, recB = 0; int bA = -1, bB = -1;
        int eA = base + threadIdx.x;
        int eB = base + 256 + threadIdx.x;
        if (eA < e1) {
            int src = es[eA], dst = ed[eA];
            bA = dst >> 7;
            recA = (u32)src | ((u32)(dst & 127) << 16);
            int p = atomicAdd(&scnt[bA], 1);
            if (p < 16) { sbuf[bA][p] = recA; bA = -1; }
        }
        if (eB < e1) {
            int src = es[eB], dst = ed[eB];
            bB = dst >> 7;
            recB = (u32)src | ((u32)(dst & 127) << 16);
            int p = atomicAdd(&scnt[bB], 1);
            if (p < 16) { sbuf[bB][p] = recB; bB = -1; }
        }
        __syncthreads();
        // flush any full 64B line
        for (int fb = threadIdx.x; fb < NB2; fb += 256) {
            if (scnt[fb] >= 16) {
                int g = atomicAdd(&gc[fb], 16);
                uint4* dp = (uint4*)(bb + (size_t)fb * CAP + g);
                uint4* sp = (uint4*)&sbuf[fb][0];
                dp[0] = sp[0]; dp[1] = sp[1]; dp[2] = sp[2]; dp[3] = sp[3];
                scnt[fb] = 0;                            // pendings re-append below
            }
        }
        __syncthreads();
        if (bA >= 0) {                                   // pending retry (count was >16)
            int p = atomicAdd(&scnt[bA], 1);
            if (p < 16) sbuf[bA][p] = recA;
            else { int g = atomicAdd(&gc[bA], 1); bb[(size_t)bA * CAP + g] = recA; }  // ultra-rare
        }
        if (bB >= 0) {
            int p = atomicAdd(&scnt[bB], 1);
            if (p < 16) sbuf[bB][p] = recB;
            else { int g = atomicAdd(&gc[bB], 1); bb[(size_t)bB * CAP + g] = recB; }
        }
        __syncthreads();
    }
    // residual (<16 per bucket) partial flush
    for (int fb = threadIdx.x; fb < NB2; fb += 256) {
        int c = scnt[fb];
        if (c > 0) {
            int g = atomicAdd(&gc[fb], c);
            for (int k = 0; k < c; ++k) bb[(size_t)fb * CAP + g + k] = sbuf[fb][k];
        }
    }
}

// ---------------- per-bucket: local degree hist + scan -> CSR scatter + nodeinfo + dinv ----------------
__global__ __launch_bounds__(256) void csr_scatter_kernel(const u32* __restrict__ binned, const int* __restrict__ gcur,
                                                          u16* __restrict__ srclist, u32* __restrict__ nodeinfo,
                                                          float* __restrict__ dinv) {
    __shared__ u32 recs[CAP];
    __shared__ int hist[128];
    __shared__ int cur[128];
    int b = blockIdx.x, t = blockIdx.y, tid = threadIdx.x;
    int node0 = b * 128;
    int tot = gcur[t * NB2 + b];
    const u32* win = binned + ((size_t)t * NB2 + b) * CAP;

    for (int i = tid; i < tot; i += 256) recs[i] = win[i];
    if (tid < 128) hist[tid] = 0;
    __syncthreads();
    for (int i = tid; i < tot; i += 256) atomicAdd(&hist[recs[i] >> 16], 1);
    __syncthreads();
    int h = 0;
    if (tid < 128) h = hist[tid];
    for (int off = 1; off < 128; off <<= 1) {
        int v = 0;
        if (tid < 128 && tid >= off) v = hist[tid - off];
        __syncthreads();
        if (tid < 128) hist[tid] += v;
        __syncthreads();
    }
    if (tid < 128) {
        int excl = hist[tid] - h;
        cur[tid] = excl;
        int node = node0 + tid;
        if (node < NN) {
            nodeinfo[t * NN + node] = (u32)(b * CAP + excl) | ((u32)h << 20);
            dinv[t * NN + node] = rsqrtf(1.0f + (float)h);
        }
    }
    __syncthreads();
    u16* sl = srclist + (size_t)t * NB2 * CAP;
    for (int i = tid; i < tot; i += 256) {
        u32 rec = recs[i];
        int d = rec >> 16;
        int p = atomicAdd(&cur[d], 1);
        sl[(size_t)b * CAP + p] = (u16)(rec & 0xFFFF);
    }
}

// ---------------- W transpose + bf16 convert (once per t) ----------------
__global__ __launch_bounds__(256) void wt_prep_kernel(const float* __restrict__ Wg, u16* __restrict__ wt) {
    int t = blockIdx.x;
    const float* w = Wg + t * FF * HH;
    u16* o = wt + (size_t)t * HH * FF;
    for (int i = threadIdx.x; i < FF * HH; i += 256) {
        int k = i >> 6, c = i & 63;
        o[c * FF + k] = f2bf(w[i]);
    }
}

// ---------------- y = (x @ Wg) * dinv via bf16 MFMA, no LDS (direct reg loads) ----------------
// block = 64 rows x 64 cols, 4 waves x 16 rows. A: two float4 from x per k0, reg-convert
// to bf16 (wave's 16-row x 512B working set is L1-resident across the k0 loop). B: bf16x8
// direct from L2-resident wt (16KB/t). No LDS, no barrier -> occupancy not LDS-capped.
__global__ __launch_bounds__(256) void xw_kernel(const float* __restrict__ x, const u16* __restrict__ wt,
                                                 const float* __restrict__ dinv, u16* __restrict__ y) {
    int t = blockIdx.y;
    int row0 = blockIdx.x * 64;
    int tid = threadIdx.x;
    int w = tid >> 6, lane = tid & 63;
    int wr = w * 16;
    int l15 = lane & 15, lg = lane >> 4;
    int arow = row0 + wr + l15;
    const float* xt = x + (size_t)t * NN * FF;
    const u16* wtt = wt + (size_t)t * HH * FF;

    f32x4 d[4] = {{0,0,0,0},{0,0,0,0},{0,0,0,0},{0,0,0,0}};
    #pragma unroll
    for (int k0 = 0; k0 < 128; k0 += 32) {
        int kb = k0 + lg * 8;
        union { bf16x8 v; u16 s[8]; } au;
        if (arow < NN) {
            float4 f0 = *reinterpret_cast<const float4*>(&xt[(size_t)arow * FF + kb]);
            float4 f1 = *reinterpret_cast<const float4*>(&xt[(size_t)arow * FF + kb + 4]);
            au.s[0] = f2bf(f0.x); au.s[1] = f2bf(f0.y); au.s[2] = f2bf(f0.z); au.s[3] = f2bf(f0.w);
            au.s[4] = f2bf(f1.x); au.s[5] = f2bf(f1.y); au.s[6] = f2bf(f1.z); au.s[7] = f2bf(f1.w);
        } else {
            au.v = (bf16x8){0,0,0,0,0,0,0,0};
        }
        #pragma unroll
        for (int n = 0; n < 4; ++n) {
            bf16x8 bf = *reinterpret_cast<const bf16x8*>(&wtt[(size_t)(n * 16 + l15) * FF + kb]);
            d[n] = __builtin_amdgcn_mfma_f32_16x16x32_bf16(au.v, bf, d[n], 0, 0, 0);
        }
    }
    // epilogue: * dinv -> bf16 row-major [N][64]
    int rbase = row0 + wr + lg * 4;
    float dv[4];
    #pragma unroll
    for (int i = 0; i < 4; ++i) {
        int grow = rbase + i;
        dv[i] = (grow < NN) ? dinv[t * NN + grow] : 0.f;
    }
    u16* yt = y + (size_t)t * NN * HH;
    #pragma unroll
    for (int n = 0; n < 4; ++n) {
        int col = n * 16 + l15;
        #pragma unroll
        for (int i = 0; i < 4; ++i) {
            int grow = rbase + i;
            if (grow < NN) yt[(size_t)grow * HH + col] = f2bf(d[n][i] * dv[i]);
        }
    }
}

// ---------------- gather-aggregate over all T (single pass, full 128B rows) ----------------
// EXACT r8 structure (best measured: 177us @ 401MB compulsory floor, 2.3TB/s).
// wave = 1 node; lane = (slot=lane>>4, quad=lane&15); 16-edge unroll, interleaved slots.
__global__ __launch_bounds__(256) void agg_kernel(const u16* __restrict__ y, const float* __restrict__ dinv,
                                                  const u32* __restrict__ nodeinfo, const u16* __restrict__ srclist,
                                                  const float* __restrict__ bg, float* __restrict__ acc) {
    int node = blockIdx.x * 4 + (threadIdx.x >> 6);
    int lane = threadIdx.x & 63;
    int sub = lane >> 4;            // edge slot 0..3
    int fo = lane & 15;             // feature quad: feats fo*4 .. fo*4+3
    float a0 = 0.f, a1 = 0.f, a2 = 0.f, a3 = 0.f;
    for (int t = 0; t < TT; ++t) {
        const u16* yt = y + (size_t)t * NN * HH;
        u32 info = nodeinfo[t * NN + node];
        int cnt = info >> 20;
        const u16* sl = srclist + (size_t)t * NB2 * CAP + (info & 0xFFFFF);
        float s0 = 0.f, s1 = 0.f, s2 = 0.f, s3 = 0.f;
        int j = 0;
        for (; j + 16 <= cnt; j += 16) {
            int e0 = sl[j + sub], e1 = sl[j + 4 + sub], e2 = sl[j + 8 + sub], e3 = sl[j + 12 + sub];
            uint2 v0 = *reinterpret_cast<const uint2*>(&yt[(size_t)e0 * HH + fo * 4]);
            uint2 v1 = *reinterpret_cast<const uint2*>(&yt[(size_t)e1 * HH + fo * 4]);
            uint2 v2 = *reinterpret_cast<const uint2*>(&yt[(size_t)e2 * HH + fo * 4]);
            uint2 v3 = *reinterpret_cast<const uint2*>(&yt[(size_t)e3 * HH + fo * 4]);
            s0 += (bflo(v0.x) + bflo(v1.x)) + (bflo(v2.x) + bflo(v3.x));
            s1 += (bfhi(v0.x) + bfhi(v1.x)) + (bfhi(v2.x) + bfhi(v3.x));
            s2 += (bflo(v0.y) + bflo(v1.y)) + (bflo(v2.y) + bflo(v3.y));
            s3 += (bfhi(v0.y) + bfhi(v1.y)) + (bfhi(v2.y) + bfhi(v3.y));
        }
        for (; j < cnt; j += 4) {
            int e = j + sub;
            uint2 v = make_uint2(0u, 0u);
            if (e < cnt) {
                int srcid = sl[e];
                v = *reinterpret_cast<const uint2*>(&yt[(size_t)srcid * HH + fo * 4]);
            }
            s0 += bflo(v.x);
            s1 += bfhi(v.x);
            s2 += bflo(v.y);
            s3 += bfhi(v.y);
        }
        s0 += __shfl_xor(s0, 16, 64); s0 += __shfl_xor(s0, 32, 64);
        s1 += __shfl_xor(s1, 16, 64); s1 += __shfl_xor(s1, 32, 64);
        s2 += __shfl_xor(s2, 16, 64); s2 += __shfl_xor(s2, 32, 64);
        s3 += __shfl_xor(s3, 16, 64); s3 += __shfl_xor(s3, 32, 64);
        // self loop (y already scaled by src dinv)
        uint2 sv = *reinterpret_cast<const uint2*>(&yt[(size_t)node * HH + fo * 4]);
        s0 += bflo(sv.x);
        s1 += bfhi(sv.x);
        s2 += bflo(sv.y);
        s3 += bfhi(sv.y);
        float dvv = dinv[t * NN + node];
        float4 bgv = *reinterpret_cast<const float4*>(&bg[t * HH + fo * 4]);
        a0 += fmaxf(dvv * s0 + bgv.x, 0.f);
        a1 += fmaxf(dvv * s1 + bgv.y, 0.f);
        a2 += fmaxf(dvv * s2 + bgv.z, 0.f);
        a3 += fmaxf(dvv * s3 + bgv.w, 0.f);
    }
    if (sub == 0) {
        float4 o = make_float4(a0, a1, a2, a3);
        *reinterpret_cast<float4*>(&acc[(size_t)node * HH + fo * 4]) = o;
    }
}

// ---------------- per-node MLP head + log_softmax ----------------
__global__ __launch_bounds__(256) void head_kernel(const float* __restrict__ acc,
                                                   const float* __restrict__ W1, const float* __restrict__ b1,
                                                   const float* __restrict__ W2, const float* __restrict__ b2,
                                                   const float* __restrict__ W3, const float* __restrict__ b3,
                                                   float* __restrict__ out) {
    __shared__ float w1[64 * 32], w2[32 * 16], w3[16 * 4], bb1[32], bb2[16], bb3[4];
    int tid = threadIdx.x;
    for (int i = tid; i < 2048; i += 256) w1[i] = W1[i];
    for (int i = tid; i < 512; i += 256) w2[i] = W2[i];
    if (tid < 64) w3[tid] = W3[tid];
    if (tid < 32) bb1[tid] = b1[tid];
    if (tid < 16) bb2[tid] = b2[tid];
    if (tid < 4) bb3[tid] = b3[tid];
    __syncthreads();
    int node = blockIdx.x * 256 + tid;
    if (node >= NN) return;

    float a[64];
    #pragma unroll
    for (int k = 0; k < 64; ++k) a[k] = acc[(size_t)node * HH + k];

    float h1[32];
    for (int j = 0; j < 32; ++j) {
        float s = bb1[j];
        #pragma unroll
        for (int k = 0; k < 64; ++k) s += a[k] * w1[k * 32 + j];
        h1[j] = fmaxf(s, 0.f);
    }
    float h2[16];
    for (int j = 0; j < 16; ++j) {
        float s = bb2[j];
        #pragma unroll
        for (int k = 0; k < 32; ++k) s += h1[k] * w2[k * 16 + j];
        h2[j] = fmaxf(s, 0.f);
    }
    float l[4];
    for (int c = 0; c < 4; ++c) {
        float s = bb3[c];
        #pragma unroll
        for (int k = 0; k < 16; ++k) s += h2[k] * w3[k * 4 + c];
        l[c] = s;
    }
    float m = fmaxf(fmaxf(l[0], l[1]), fmaxf(l[2], l[3]));
    float sum = 0.f;
    #pragma unroll
    for (int c = 0; c < 4; ++c) sum += expf(l[c] - m);
    float lse = logf(sum);
    float4 o;
    o.x = l[0] - m - lse; o.y = l[1] - m - lse; o.z = l[2] - m - lse; o.w = l[3] - m - lse;
    *reinterpret_cast<float4*>(&out[(size_t)node * CC]) = o;
}

extern "C" void kernel_launch(void* const* d_in, const int* in_sizes, int n_in,
                              void* d_out, int out_size, void* d_ws, size_t ws_size,
                              hipStream_t stream) {
    const float* x    = (const float*)d_in[0];
    const int*  edges = (const int*)d_in[1];
    const float* Wg   = (const float*)d_in[2];
    const float* bg   = (const float*)d_in[3];
    const float* W1   = (const float*)d_in[4];
    const float* b1   = (const float*)d_in[5];
    const float* W2   = (const float*)d_in[6];
    const float* b2   = (const float*)d_in[7];
    const float* W3   = (const float*)d_in[8];
    const float* b3   = (const float*)d_in[9];
    float* out = (float*)d_out;

    char* ws = (char*)d_ws;
    size_t o = 0;
    int* gcur      = (int*)(ws + o); o += (size_t)TT * NB2 * 4;            // 12.5 KB
    o = (o + 255) & ~(size_t)255;
    float* dinv    = (float*)(ws + o); o += (size_t)TT * NN * 4;           // 1.6 MB
    u32* nodeinfo  = (u32*)(ws + o); o += (size_t)TT * NN * 4;             // 1.6 MB
    o = (o + 255) & ~(size_t)255;
    u16* wt        = (u16*)(ws + o); o += (size_t)TT * HH * FF * 2;        // 128 KB
    o = (o + 255) & ~(size_t)255;
    u32* binned    = (u32*)(ws + o); o += (size_t)TT * NB2 * CAP * 4;      // 32.0 MB
    u16* srclist   = (u16*)(ws + o); o += (size_t)TT * NB2 * CAP * 2;      // 16.0 MB
    u16* y         = (u16*)(ws + o); o += (size_t)TT * NN * HH * 2;        // 51.2 MB
    float* acc     = (float*)(ws + o); o += (size_t)NN * HH * 4;           // 12.8 MB
    // total ~115 MB

    hipMemsetAsync(gcur, 0, (size_t)TT * NB2 * 4, stream);

    multisplit_kernel<<<BPT * TT, 256, 0, stream>>>(edges, gcur, binned);

    dim3 gsc(NB2, TT);
    csr_scatter_kernel<<<gsc, 256, 0, stream>>>(binned, gcur, srclist, nodeinfo, dinv);

    wt_prep_kernel<<<TT, 256, 0, stream>>>(Wg, wt);

    dim3 gx(782, TT);
    xw_kernel<<<gx, 256, 0, stream>>>(x, wt, dinv, y);

    agg_kernel<<<12500, 256, 0, stream>>>(y, dinv, nodeinfo, srclist, bg, acc);

    head_kernel<<<196, 256, 0, stream>>>(acc, W1, b1, W2, b2, W3, b3, out);
}